// Round 7
// baseline (76.777 us; speedup 1.0000x reference)
//
#include <hip/hip_runtime.h>
#include <math.h>

// Problem constants (from reference):
// x: (32, 256, 112, 112) fp32, W: (1, 2, 7, 7) fp32, out: (32, 1, 112, 112) fp32
#define BATCH 32
#define CH    256
#define HH    112
#define WW    112
#define HW    (HH * WW)     // 12544
#define HW4   (HW / 4)      // 3136 = 7 * 448

#define CHUNK 448           // float4s per block (7 waves x 64 lanes)

// native clang vector type — accepted by __builtin_nontemporal_load
typedef float f32x4 __attribute__((ext_vector_type(4)));

// ---------------------------------------------------------------------------
// Kernel 1: channel-wise mean + max reduction.
// Block = 448 threads (7 waves), each thread owns one float4 spatial position.
// Per channel step the block reads 448 x 16B = 7 KiB contiguous.
//  - per-block channel-start stagger (r6, +7us): decorrelates HBM channel
//    phase across the 224 concurrent blocks.
//  - nontemporal loads (r6): read-once stream, don't thrash L3.
//  - NEW (r7): raw s_barrier every 8 channels. 7 waves on 4 SIMDs = [2,2,2,1]
//    -> the lone wave issues 2x faster and drifts ~1MB ahead, splitting the
//    block's contiguous 7KiB step into 7 distant 1KiB streams (DRAM row
//    thrash). Raw barrier (NO vmcnt drain, waves share no data here) caps
//    drift at 8 channels while loads stay in flight across it.
// ---------------------------------------------------------------------------
__global__ __launch_bounds__(448) void sa_pool_kernel(
    const f32x4* __restrict__ x4,
    f32x4* __restrict__ avg4,
    f32x4* __restrict__ max4)
{
    int tid = threadIdx.x;
    int b   = blockIdx.y;
    int q   = blockIdx.x * CHUNK + tid;   // float4 index within the HxW plane

    const f32x4* p = x4 + (size_t)b * (CH * HW4) + q;

    // stagger channel start per block to spread DRAM channel phase
    int c0 = (blockIdx.x * 37 + blockIdx.y * 11) & (CH - 1);

    f32x4 s = (f32x4){0.f, 0.f, 0.f, 0.f};
    f32x4 m = (f32x4){-INFINITY, -INFINITY, -INFINITY, -INFINITY};

    for (int cc = 0; cc < CH; cc += 8) {
        #pragma unroll
        for (int u = 0; u < 8; ++u) {
            int c = cc + u + c0;
            c -= (c >= CH) ? CH : 0;
            f32x4 v = __builtin_nontemporal_load(p + (size_t)c * HW4);
            s.x += v.x; s.y += v.y; s.z += v.z; s.w += v.w;
            m.x = fmaxf(m.x, v.x);
            m.y = fmaxf(m.y, v.y);
            m.z = fmaxf(m.z, v.z);
            m.w = fmaxf(m.w, v.w);
        }
        // wave-pacing barrier: raw s_barrier, no waitcnt drain
        __builtin_amdgcn_s_barrier();
    }

    const float inv = 1.0f / (float)CH;
    f32x4 a;
    a.x = s.x * inv; a.y = s.y * inv; a.z = s.z * inv; a.w = s.w * inv;

    int g = b * HW4 + q;
    avg4[g] = a;
    max4[g] = m;
}

// ---------------------------------------------------------------------------
// Kernel 2: 7x7 conv (2 in-ch -> 1 out-ch, pad 3) + sigmoid (unchanged).
// 16x16 output tile / block; halo tile 22x22 per channel in LDS; weights in
// LDS. 112/16 = 7 exactly -> no output bounds checks.
// ---------------------------------------------------------------------------
#define TILE 16
#define TW   (TILE + 6)     // 22

__global__ __launch_bounds__(256) void sa_conv_kernel(
    const float* __restrict__ avgp,
    const float* __restrict__ maxp,
    const float* __restrict__ wt,    // [2][7][7] flat (O=1, OIHW)
    float* __restrict__ out)
{
    __shared__ float t0[TW][TW];
    __shared__ float t1[TW][TW];
    __shared__ float w[2][49];

    int tid = threadIdx.x;
    int b   = blockIdx.z;
    int ty0 = blockIdx.y * TILE;
    int tx0 = blockIdx.x * TILE;

    if (tid < 98) w[tid / 49][tid % 49] = wt[tid];

    const float* ap = avgp + b * HW;
    const float* mp = maxp + b * HW;

    for (int idx = tid; idx < TW * TW; idx += 256) {
        int iy = idx / TW;
        int ix = idx - iy * TW;
        int gy = ty0 + iy - 3;
        int gx = tx0 + ix - 3;
        bool ok = (gy >= 0) && (gy < HH) && (gx >= 0) && (gx < WW);
        int gofs = gy * WW + gx;
        t0[iy][ix] = ok ? ap[gofs] : 0.0f;
        t1[iy][ix] = ok ? mp[gofs] : 0.0f;
    }
    __syncthreads();

    int oy = tid >> 4;          // 0..15
    int ox = tid & 15;          // 0..15

    float acc = 0.0f;
    #pragma unroll
    for (int i = 0; i < 7; ++i) {
        #pragma unroll
        for (int j = 0; j < 7; ++j) {
            acc += w[0][i * 7 + j] * t0[oy + i][ox + j];
            acc += w[1][i * 7 + j] * t1[oy + i][ox + j];
        }
    }

    float y = 1.0f / (1.0f + expf(-acc));
    out[b * HW + (ty0 + oy) * WW + (tx0 + ox)] = y;
}

// ---------------------------------------------------------------------------
extern "C" void kernel_launch(void* const* d_in, const int* in_sizes, int n_in,
                              void* d_out, int out_size, void* d_ws, size_t ws_size,
                              hipStream_t stream)
{
    const float* x  = (const float*)d_in[0];
    const float* wt = (const float*)d_in[1];
    float* out = (float*)d_out;

    // workspace: avg plane then max plane, each BATCH*HW floats (1.6 MB each)
    float* avgp = (float*)d_ws;
    float* maxp = avgp + (size_t)BATCH * HW;

    // Kernel 1: 7 x 32 = 224 blocks of 448 threads (7 KiB contiguous / c-step)
    dim3 grid1(HW4 / CHUNK, BATCH);
    sa_pool_kernel<<<grid1, CHUNK, 0, stream>>>(
        (const f32x4*)x, (f32x4*)avgp, (f32x4*)maxp);

    // Kernel 2: 7x7 tiles, 32 batches
    dim3 grid2(WW / TILE, HH / TILE, BATCH);
    sa_conv_kernel<<<grid2, 256, 0, stream>>>(avgp, maxp, wt, out);
}